// Round 2
// 159.714 us; speedup vs baseline: 1.0380x; 1.0380x over previous
//
#include <hip/hip_runtime.h>
#include <math.h>

#define B    256
#define I    1152
#define O    10
#define DIN  8
#define DOUT 16
#define OE   160          // O*DOUT
#define XROW 9216         // I*DIN (also K of the s-GEMM)
#define WROW 1280         // O*DIN*DOUT
#define PSPLIT 72         // split-K partials (sp = 11.8 MB, fits proven ws budget)
#define CHUNK  16         // i per spart block
#define SI     8          // i per staging round (K-window 64)

#define WPREP_BLOCKS ((I * OE) / 256)   // 720

typedef __attribute__((ext_vector_type(8))) short short8;
typedef __attribute__((ext_vector_type(4))) float floatx4;

__device__ __forceinline__ unsigned short f2bf(float f) {
    unsigned u = __builtin_bit_cast(unsigned, f);
    u += 0x7fffu + ((u >> 16) & 1u);          // RNE
    return (unsigned short)(u >> 16);
}
__device__ __forceinline__ float bf2f(unsigned short h) {
    unsigned u = ((unsigned)h) << 16;
    return __builtin_bit_cast(float, u);
}

// 8 consecutive fp32 -> bf16 hi/lo pair (RNE), in registers.
__device__ __forceinline__ void split8(const float* __restrict__ xp,
                                       short8& h8, short8& l8)
{
    float4 v0 = *(const float4*)xp;
    float4 v1 = *(const float4*)(xp + 4);
    float v[8] = {v0.x, v0.y, v0.z, v0.w, v1.x, v1.y, v1.z, v1.w};
#pragma unroll
    for (int d = 0; d < 8; ++d) {
        unsigned short h = f2bf(v[d]);
        h8[d] = (short)h;
        l8[d] = (short)f2bf(v[d] - bf2f(h));
    }
}

// ---------------------------------------------------------------------------
// WPREP: transpose W -> Wt[i][oe][d] fp32 (d-contiguous). One-time cost.
// All later W reads (spart staging, agree) become coalesced b128 pairs.
// ---------------------------------------------------------------------------
__global__ __launch_bounds__(256) void wprep_kernel(
    const float* __restrict__ W, float* __restrict__ Wt)
{
    int g  = blockIdx.x * 256 + threadIdx.x;  // (i, oe) pair
    int i  = g / OE;
    int oe = g - i * OE;
    int o  = oe >> 4;
    int e  = oe & 15;
    const float* wp = W + (size_t)i * WROW + o * (DIN * DOUT) + e;
    float4 a, b;
    a.x = wp[0 * DOUT]; a.y = wp[1 * DOUT]; a.z = wp[2 * DOUT]; a.w = wp[3 * DOUT];
    b.x = wp[4 * DOUT]; b.y = wp[5 * DOUT]; b.z = wp[6 * DOUT]; b.w = wp[7 * DOUT];
    float4* dst = (float4*)(Wt + (size_t)g * 8);
    dst[0] = a;
    dst[1] = b;                               // coalesced 32 B/lane write
}

// ---------------------------------------------------------------------------
// SPART v5: MFMA bf16 hi/lo split-K GEMM.
//   s[b,oe] = sum_k x[b,k] * (c[i,o]*W)[k,oe], hi/lo split both sides,
//   3 MFMAs per tile-step: xh*wh + xh*wl + xl*wh  (xl*wl dropped, ~2^-18)
// vs v3 (last passing version):
//  - X fragments: direct global fp32 loads + in-register RNE split (each
//    staged LDS chunk had exactly one consumer -> round-trip was overhead;
//    also deletes the xsplit prep kernel and 9.4 MB of workspace).
//  - W staged from pre-transposed Wt (d-contiguous): 2 coalesced b128 loads
//    instead of 8 stride-64B dwords per (oe,i) group.
//  - LDS 52 -> 20.5 KB/block => >=4 co-resident blocks/CU.
// grid = 4*PSPLIT: bid -> ic=bid>>2, mb=(bid>>1)&1 (128 b-rows), nb=bid&1.
// Block = 4 waves; wave tile M=32 x N=80 (2x5 tiles of 16x16, acc 40 VGPR).
// W LDS XOR-swizzle: 16B chunk c at row r stored at chunk c^(r&7) ->
// conflict-free b128 reads/writes.
// ---------------------------------------------------------------------------
__global__ __launch_bounds__(256) void spart_mfma(
    const float* __restrict__ x,
    const float* __restrict__ Wt, const float* __restrict__ c,
    float* __restrict__ sp, int first)
{
    __shared__ unsigned short Wh[80 * 64], Wl[80 * 64];    // [oe-local][k-window]

    int bid = blockIdx.x;
    int ic  = bid >> 2;
    int mb  = (bid >> 1) & 1;
    int nb  = bid & 1;
    int b0  = mb * 128;
    int oe0 = nb * 80;
    int i0  = ic * CHUNK;

    int t    = threadIdx.x;
    int w    = t >> 6;
    int lane = t & 63;
    int l15  = lane & 15;
    int q    = lane >> 4;

    floatx4 acc[2][5];
#pragma unroll
    for (int mt = 0; mt < 2; ++mt)
#pragma unroll
        for (int nt = 0; nt < 5; ++nt) acc[mt][nt] = (floatx4)(0.f);

#pragma unroll
    for (int round = 0; round < CHUNK / SI; ++round) {
        int si0 = i0 + round * SI;
        if (round) __syncthreads();

        // ---- X fragments: direct global fp32 loads + in-register split ----
        short8 ah[2][2], al[2][2];                // [ks][mt]
#pragma unroll
        for (int ks = 0; ks < 2; ++ks)
#pragma unroll
            for (int mt = 0; mt < 2; ++mt) {
                const float* xp = x + (size_t)(b0 + w * 32 + mt * 16 + l15) * XROW
                                + (size_t)si0 * 8 + (ks << 5) + (q << 3);
                split8(xp, ah[ks][mt], al[ks][mt]);
            }

        // ---- stage W: coalesced loads from Wt, scale by c, split hi/lo ----
#pragma unroll
        for (int r = 0; r < 3; ++r) {
            int p = t + 256 * r;                  // (oe-local, i-local) pair
            if (p < 640) {
                int oeL = p % 80;
                int iL  = p / 80;                 // 0..7
                int o   = (oe0 + oeL) >> 4;
                const float* wp = Wt + ((size_t)(si0 + iL) * OE + oe0 + oeL) * 8;
                float cv = first ? 0.1f : c[(si0 + iL) * O + o];
                float4 w0 = *(const float4*)wp;
                float4 w1 = *(const float4*)(wp + 4);
                float wv[8] = {w0.x, w0.y, w0.z, w0.w, w1.x, w1.y, w1.z, w1.w};
                short8 hv, lv;
#pragma unroll
                for (int d = 0; d < 8; ++d) {
                    float s = wv[d] * cv;
                    unsigned short h = f2bf(s);
                    hv[d] = (short)h;
                    lv[d] = (short)f2bf(s - bf2f(h));
                }
                int off = oeL * 64 + ((iL ^ (oeL & 7)) << 3);
                *(short8*)(Wh + off) = hv;
                *(short8*)(Wl + off) = lv;
            }
        }
        __syncthreads();

        // ---- 2 K-steps of 32 over the staged window ----
#pragma unroll
        for (int ks = 0; ks < 2; ++ks) {
#pragma unroll
            for (int nt = 0; nt < 5; ++nt) {
                int rn  = nt * 16 + l15;
                int off = rn * 64 + ((((ks << 2) + q) ^ (rn & 7)) << 3);
                short8 bh = *(const short8*)(Wh + off);
                short8 bl = *(const short8*)(Wl + off);
#pragma unroll
                for (int mt = 0; mt < 2; ++mt) {
                    acc[mt][nt] = __builtin_amdgcn_mfma_f32_16x16x32_bf16(ah[ks][mt], bh, acc[mt][nt], 0, 0, 0);
                    acc[mt][nt] = __builtin_amdgcn_mfma_f32_16x16x32_bf16(ah[ks][mt], bl, acc[mt][nt], 0, 0, 0);
                    acc[mt][nt] = __builtin_amdgcn_mfma_f32_16x16x32_bf16(al[ks][mt], bh, acc[mt][nt], 0, 0, 0);
                }
            }
        }
    }

    // ---- epilogue: C/D layout col=lane&15, row=(lane>>4)*4+reg (m89/m91) ----
    float* base = sp + (size_t)ic * (B * OE);
#pragma unroll
    for (int mt = 0; mt < 2; ++mt) {
        int row0 = b0 + w * 32 + mt * 16 + q * 4;
#pragma unroll
        for (int nt = 0; nt < 5; ++nt) {
            int col = oe0 + nt * 16 + l15;
#pragma unroll
            for (int reg = 0; reg < 4; ++reg)
                base[(row0 + reg) * OE + col] = acc[mt][nt][reg];
        }
    }
}

// ---------------------------------------------------------------------------
// VRED: sum P partials + squash over e (16 lanes), write v (or final output).
// ---------------------------------------------------------------------------
__global__ __launch_bounds__(256) void vred_kernel(
    const float* __restrict__ sp, float* __restrict__ dst)
{
    int g = blockIdx.x * 256 + threadIdx.x;     // [b][o][e] flat
    float s = 0.f;
#pragma unroll 8
    for (int ic = 0; ic < PSPLIT; ++ic) s += sp[(size_t)ic * (B * OE) + g];

    float ss = s * s;
    ss += __shfl_xor(ss, 1, 16);
    ss += __shfl_xor(ss, 2, 16);
    ss += __shfl_xor(ss, 4, 16);
    ss += __shfl_xor(ss, 8, 16);
    float f = sqrtf(ss) / (1.f + ss);           // squash factor
    dst[g] = s * f;
}

// ---------------------------------------------------------------------------
// AGREE (+ fused b-update and softmax -> c). One block per i, 320 threads.
// W reads from transposed Wt (coalesced b128 pairs).
// ---------------------------------------------------------------------------
__global__ __launch_bounds__(320) void agree_kernel(
    const float* __restrict__ x, const float* __restrict__ Wt,
    const float* __restrict__ v, float* __restrict__ blog,
    float* __restrict__ c, int first)
{
    int i  = blockIdx.x;
    int t  = threadIdx.x;
    int dg = (t >= OE) ? 1 : 0;
    int oe = t - dg * OE;

    __shared__ float4 Xl[B][2];        // x[b, i, 0:8] as two float4 (8 KB)
    __shared__ float  G[DIN * OE];
    __shared__ float  brow[O];

#pragma unroll
    for (int k = 0; k < 2; ++k) {
        int idx = t + 320 * k;
        if (idx < 512) {
            int r = idx >> 1;
            int h = idx & 1;
            Xl[r][h] = *(const float4*)(x + (size_t)r * XROW + i * DIN + h * 4);
        }
    }
    __syncthreads();

    float a0 = 0.f, a1 = 0.f, a2 = 0.f, a3 = 0.f;
    const float* vp = v + oe;
#pragma unroll 8
    for (int bb = 0; bb < B; ++bb) {
        float  vv = vp[bb * OE];
        float4 xq = Xl[bb][dg];
        a0 = fmaf(xq.x, vv, a0);
        a1 = fmaf(xq.y, vv, a1);
        a2 = fmaf(xq.z, vv, a2);
        a3 = fmaf(xq.w, vv, a3);
    }

    int d0 = dg * 4;
    G[(d0 + 0) * OE + oe] = a0;
    G[(d0 + 1) * OE + oe] = a1;
    G[(d0 + 2) * OE + oe] = a2;
    G[(d0 + 3) * OE + oe] = a3;
    __syncthreads();

    if (t < OE) {
        int o = t >> 4;
        const float* wr = Wt + ((size_t)i * OE + t) * 8;
        float4 wa = *(const float4*)wr;
        float4 wb = *(const float4*)(wr + 4);
        float p = 0.f;
        p = fmaf(wa.x, G[0 * OE + t], p);
        p = fmaf(wa.y, G[1 * OE + t], p);
        p = fmaf(wa.z, G[2 * OE + t], p);
        p = fmaf(wa.w, G[3 * OE + t], p);
        p = fmaf(wb.x, G[4 * OE + t], p);
        p = fmaf(wb.y, G[5 * OE + t], p);
        p = fmaf(wb.z, G[6 * OE + t], p);
        p = fmaf(wb.w, G[7 * OE + t], p);
        p += __shfl_xor(p, 8, 16);
        p += __shfl_xor(p, 4, 16);
        p += __shfl_xor(p, 2, 16);
        p += __shfl_xor(p, 1, 16);
        if ((t & 15) == 0) {
            float bo = first ? 0.f : blog[i * O + o];
            bo += p * (1.f / (float)B);
            blog[i * O + o] = bo;
            brow[o] = bo;
        }
    }
    __syncthreads();

    if (t == 0) {
        float m = brow[0];
#pragma unroll
        for (int o = 1; o < O; ++o) m = fmaxf(m, brow[o]);
        float ex[O];
        float sum = 0.f;
#pragma unroll
        for (int o = 0; o < O; ++o) { ex[o] = __expf(brow[o] - m); sum += ex[o]; }
        float inv = 1.f / sum;
#pragma unroll
        for (int o = 0; o < O; ++o) c[i * O + o] = ex[o] * inv;
    }
}

// ---------------------------------------------------------------------------
extern "C" void kernel_launch(void* const* d_in, const int* in_sizes, int n_in,
                              void* d_out, int out_size, void* d_ws, size_t ws_size,
                              hipStream_t stream)
{
    const float* x = (const float*)d_in[0];   // [256,1152,8]
    const float* W = (const float*)d_in[1];   // [1152,10,8,16]
    float* out = (float*)d_out;               // [256,10,16,1] flat = 40960

    // workspace layout (floats): blog | c | v | Wt 5.9MB | sp 11.8MB  (~17.8MB)
    float* blog = (float*)d_ws;
    float* cbuf = blog + I * O;
    float* vbuf = cbuf + I * O;
    float* Wt   = vbuf + B * OE;
    float* sp   = Wt + (size_t)I * OE * DIN;

    // ---- one-time: transpose W (iteration-invariant) ----
    wprep_kernel<<<WPREP_BLOCKS, 256, 0, stream>>>(W, Wt);

    dim3 gs(4 * PSPLIT), bs(256);
    // ---- iteration 1 (b=0 -> c uniform 0.1, folded via `first`) ----
    spart_mfma<<<gs, bs, 0, stream>>>(x, Wt, cbuf, sp, 1);
    vred_kernel<<<160, 256, 0, stream>>>(sp, vbuf);
    agree_kernel<<<I, 320, 0, stream>>>(x, Wt, vbuf, blog, cbuf, 1);
    // ---- iteration 2 ----
    spart_mfma<<<gs, bs, 0, stream>>>(x, Wt, cbuf, sp, 0);
    vred_kernel<<<160, 256, 0, stream>>>(sp, vbuf);
    agree_kernel<<<I, 320, 0, stream>>>(x, Wt, vbuf, blog, cbuf, 0);
    // ---- iteration 3 (squash straight into d_out) ----
    spart_mfma<<<gs, bs, 0, stream>>>(x, Wt, cbuf, sp, 0);
    vred_kernel<<<160, 256, 0, stream>>>(sp, out);
}